// Round 11
// baseline (354.262 us; speedup 1.0000x reference)
//
#include <hip/hip_runtime.h>

// Problem constants
#define NB 256
#define NDF 768
#define NQ 96
#define NS 361
#define LDT 40        // Q staging stride (bf16 elems): 80B rows
#define LDP 392       // K2 attn LDS stride (bf16 elems): 784B rows, 16B-aligned
#define WSROW 368     // ws logits row stride (bf16 elems): 184 dwords, 16B-aligned
#define WS_LOG_BYTES ((size_t)NB * NQ * WSROW * 2)

typedef short bf16x8_t __attribute__((ext_vector_type(8)));
typedef float f32x4_t __attribute__((ext_vector_type(4)));
typedef float f32x4u_t __attribute__((ext_vector_type(4), aligned(4)));
typedef unsigned int u32x4_t __attribute__((ext_vector_type(4)));

// [b.hi16 | a.hi16] -> one dword (1 v_perm_b32)
__device__ __forceinline__ unsigned pack_hi(unsigned b_, unsigned a_) {
    return __builtin_amdgcn_perm(b_, a_, 0x07060302u);
}
__device__ __forceinline__ unsigned short f2bf(float x) {   // RNE
    unsigned u = __float_as_uint(x);
    u += 0x7FFFu + ((u >> 16) & 1u);
    return (unsigned short)(u >> 16);
}
__device__ __forceinline__ float bf2f(unsigned short h) {
    return __uint_as_float(((unsigned)h) << 16);
}

// split-bf16 convert: 8 fp32 -> hi bf16x8 (trunc) + lo bf16x8 (residual, trunc)
__device__ __forceinline__ void cvt8(const float* x, bf16x8_t& hi, bf16x8_t& lo) {
    unsigned uh[8]; float fl[8];
#pragma unroll
    for (int j = 0; j < 8; ++j) {
        unsigned u = __float_as_uint(x[j]);
        uh[j] = u;
        fl[j] = x[j] - __uint_as_float(u & 0xFFFF0000u);
    }
    u32x4_t h, l;
    h[0] = pack_hi(uh[1], uh[0]); h[1] = pack_hi(uh[3], uh[2]);
    h[2] = pack_hi(uh[5], uh[4]); h[3] = pack_hi(uh[7], uh[6]);
    l[0] = pack_hi(__float_as_uint(fl[1]), __float_as_uint(fl[0]));
    l[1] = pack_hi(__float_as_uint(fl[3]), __float_as_uint(fl[2]));
    l[2] = pack_hi(__float_as_uint(fl[5]), __float_as_uint(fl[4]));
    l[3] = pack_hi(__float_as_uint(fl[7]), __float_as_uint(fl[6]));
    hi = __builtin_bit_cast(bf16x8_t, h);
    lo = __builtin_bit_cast(bf16x8_t, l);
}

// LDS-only barrier: orders LDS ops; global loads (VMEM=0x20) may cross freely.
__device__ __forceinline__ void block_sync_lds() {
    __builtin_amdgcn_sched_barrier(0x20);
    asm volatile("s_waitcnt lgkmcnt(0)" ::: "memory");
    __builtin_amdgcn_sched_barrier(0x20);
    __builtin_amdgcn_s_barrier();
    __builtin_amdgcn_sched_barrier(0x20);
}

// ================= K1: GEMM1 (split-bf16) + softmax over q =================
// grid NB*2 (batch, s-half of 192), 384 thr = 6 waves; wave: 2 s-tiles x 6 q-tiles.
// ctx B-fragments load DIRECTLY from global into registers, 2-phase pipelined:
// per 64-row iteration: issue ctxB(k+32)+Q(k+64) -> pin -> MFMA(ctxA) ->
// issue ctxA(k+64) -> pin -> MFMA(ctxB) -> stage Q -> ONE lds barrier.
// Every ctx load gets >=1 MFMA phase of latency cover; ctxA a full iteration.
// MODE 1: bf16 logits2 -> ws.  MODE 0: softmaxq*4 fp32 -> Aout (fallback).
template<int MODE>
__global__ __launch_bounds__(384, 3) void k1_gemm1_softmaxq(
    const float* __restrict__ Qg, const float* __restrict__ Cg,
    unsigned short* __restrict__ WsLog, float* __restrict__ AoutF)
{
    __shared__ __align__(16) unsigned short sQhi[2][2][NQ * LDT];   // [buf][half32]
    __shared__ __align__(16) unsigned short sQlo[2][2][NQ * LDT];   // 61440 B total

    // XCD-pairing swizzle (grid 512 = 8 xcd * 32 batch-groups * 2 halves)
    const int x = blockIdx.x;
    const int b = (x & 7) * 32 + (x >> 4);
    const int h = (x >> 3) & 1;

    const int tid = threadIdx.x;
    const int wv = tid >> 6;
    const int lane = tid & 63;
    const int ll = lane & 15;
    const int lg = lane >> 4;
    const int s0 = 192 * h;
    // Q staging geometry: thread owns column qq and k-octet koct (96*4 = 384 units)
    const int qq = tid % 96;
    const int koct = tid / 96;         // 0..3
    // B-fragment columns for this lane (clamped; fake s>=NS computes garbage, never written)
    const int sc0 = min(s0 + 32 * wv + ll, NS - 1);
    const int sc1 = min(s0 + 32 * wv + 16 + ll, NS - 1);

    const float* __restrict__ qg = Qg + (size_t)b * NDF * NQ;   // [768][96]
    const float* __restrict__ cg = Cg + (size_t)b * NDF * NS;   // [768][361]

    f32x4_t acc[6][2];
#pragma unroll
    for (int i = 0; i < 6; ++i)
#pragma unroll
        for (int j = 0; j < 2; ++j) acc[i][j] = (f32x4_t)0.0f;

    float cA[16], cB[16], qv[16];

#define LOADQ64(K0) { \
    _Pragma("unroll") \
    for (int t = 0; t < 2; ++t) \
        _Pragma("unroll") \
        for (int j = 0; j < 8; ++j) \
            qv[8 * t + j] = qg[((K0) + 32 * t + 8 * koct + j) * NQ + qq]; }

#define STAGEQ64(BUF) { \
    bf16x8_t h0, l0, h1, l1; \
    cvt8(qv, h0, l0); cvt8(qv + 8, h1, l1); \
    *(bf16x8_t*)&sQhi[BUF][0][qq * LDT + 8 * koct] = h0; \
    *(bf16x8_t*)&sQlo[BUF][0][qq * LDT + 8 * koct] = l0; \
    *(bf16x8_t*)&sQhi[BUF][1][qq * LDT + 8 * koct] = h1; \
    *(bf16x8_t*)&sQlo[BUF][1][qq * LDT + 8 * koct] = l1; }

#define LOADCTX(K0, R) { \
    _Pragma("unroll") \
    for (int j = 0; j < 8; ++j) \
        R[j] = cg[(size_t)((K0) + 8 * lg + j) * NS + sc0]; \
    _Pragma("unroll") \
    for (int j = 0; j < 8; ++j) \
        R[8 + j] = cg[(size_t)((K0) + 8 * lg + j) * NS + sc1]; }

#define MFMAPHASE(R, BUF, HALF) { \
    bf16x8_t B0h, B0l, B1h, B1l; \
    cvt8(R, B0h, B0l); \
    cvt8(R + 8, B1h, B1l); \
    _Pragma("unroll") \
    for (int mt = 0; mt < 6; ++mt) { \
        bf16x8_t Ah = *(const bf16x8_t*)&sQhi[BUF][HALF][(16 * mt + ll) * LDT + 8 * lg]; \
        bf16x8_t Al = *(const bf16x8_t*)&sQlo[BUF][HALF][(16 * mt + ll) * LDT + 8 * lg]; \
        acc[mt][0] = __builtin_amdgcn_mfma_f32_16x16x32_bf16(Ah, B0h, acc[mt][0], 0, 0, 0); \
        acc[mt][0] = __builtin_amdgcn_mfma_f32_16x16x32_bf16(Ah, B0l, acc[mt][0], 0, 0, 0); \
        acc[mt][0] = __builtin_amdgcn_mfma_f32_16x16x32_bf16(Al, B0h, acc[mt][0], 0, 0, 0); \
        acc[mt][1] = __builtin_amdgcn_mfma_f32_16x16x32_bf16(Ah, B1h, acc[mt][1], 0, 0, 0); \
        acc[mt][1] = __builtin_amdgcn_mfma_f32_16x16x32_bf16(Ah, B1l, acc[mt][1], 0, 0, 0); \
        acc[mt][1] = __builtin_amdgcn_mfma_f32_16x16x32_bf16(Al, B1h, acc[mt][1], 0, 0, 0); } }

    LOADQ64(0);
    LOADCTX(0, cA);
    STAGEQ64(0);
    block_sync_lds();

    for (int k0 = 0; k0 < NDF; k0 += 64) {
        const int cur = (k0 >> 6) & 1;
        LOADCTX(k0 + 32, cB);                       // phase-B ctx: covered by phase A
        if (k0 + 64 < NDF) LOADQ64(k0 + 64);        // Q prefetch: covered by whole iter
        __builtin_amdgcn_sched_barrier(0);          // PIN: loads issue before MFMA
        MFMAPHASE(cA, cur, 0);
        if (k0 + 64 < NDF) LOADCTX(k0 + 64, cA);    // next-iter ctx A: full iter cover
        __builtin_amdgcn_sched_barrier(0);          // PIN
        MFMAPHASE(cB, cur, 1);
        if (k0 + 64 < NDF) STAGEQ64(cur ^ 1);
        block_sync_lds();
    }
#undef LOADQ64
#undef STAGEQ64
#undef LOADCTX
#undef MFMAPHASE

    // softmax over q (per s-col), fold *4; D layout: col(s)=ll, row(q)=16mt+4lg+r
#pragma unroll
    for (int nt = 0; nt < 2; ++nt) {
        float m = -3.0e38f;
#pragma unroll
        for (int mt = 0; mt < 6; ++mt)
#pragma unroll
            for (int r = 0; r < 4; ++r) m = fmaxf(m, acc[mt][nt][r]);
        m = fmaxf(m, __shfl_xor(m, 16));
        m = fmaxf(m, __shfl_xor(m, 32));
        float sum = 0.0f;
#pragma unroll
        for (int mt = 0; mt < 6; ++mt)
#pragma unroll
            for (int r = 0; r < 4; ++r) {
                float e = __expf(acc[mt][nt][r] - m);
                acc[mt][nt][r] = e;
                sum += e;
            }
        sum += __shfl_xor(sum, 16);
        sum += __shfl_xor(sum, 32);
        float inv = 4.0f / sum;     // fold TEMP1
#pragma unroll
        for (int mt = 0; mt < 6; ++mt)
#pragma unroll
            for (int r = 0; r < 4; ++r) acc[mt][nt][r] *= inv;
    }

    if constexpr (MODE >= 1) {
        unsigned short* wr = WsLog + (size_t)b * NQ * WSROW;
#pragma unroll
        for (int mt = 0; mt < 6; ++mt)
#pragma unroll
            for (int nt = 0; nt < 2; ++nt)
#pragma unroll
                for (int r = 0; r < 4; ++r) {
                    int q = 16 * mt + 4 * lg + r;
                    int s = s0 + 32 * wv + 16 * nt + ll;
                    if (s < NS) wr[q * WSROW + s] = f2bf(acc[mt][nt][r]);
                }
    } else {
        float* aout = AoutF + (size_t)b * NQ * NS;
#pragma unroll
        for (int mt = 0; mt < 6; ++mt)
#pragma unroll
            for (int nt = 0; nt < 2; ++nt)
#pragma unroll
                for (int r = 0; r < 4; ++r) {
                    int q = 16 * mt + 4 * lg + r;
                    int s = s0 + 32 * wv + 16 * nt + ll;
                    if (s < NS) aout[(size_t)q * NS + s] = acc[mt][nt][r];
                }
    }
}

// ================= K15 (fallback only): in-place softmax over s =================
__global__ __launch_bounds__(256) void k15_softmaxs(float* __restrict__ Aout)
{
    const int b = blockIdx.x;
    const int q = blockIdx.y * 4 + (threadIdx.x >> 6);
    const int lane = threadIdx.x & 63;
    float* __restrict__ row = Aout + ((size_t)b * NQ + q) * NS;
    const int c0 = 6 * lane;

    float v[6];
#pragma unroll
    for (int i = 0; i < 6; ++i) v[i] = (c0 + i < NS) ? row[c0 + i] : -INFINITY;
    float m = v[0];
#pragma unroll
    for (int i = 1; i < 6; ++i) m = fmaxf(m, v[i]);
#pragma unroll
    for (int o = 1; o < 64; o <<= 1) m = fmaxf(m, __shfl_xor(m, o));
    float e[6], sum = 0.0f;
#pragma unroll
    for (int i = 0; i < 6; ++i) { e[i] = __expf(v[i] - m); sum += e[i]; }
#pragma unroll
    for (int o = 1; o < 64; o <<= 1) sum += __shfl_xor(sum, o);
    float inv = 1.0f / sum;
#pragma unroll
    for (int i = 0; i < 6; ++i) if (c0 + i < NS) row[c0 + i] = e[i] * inv;
}

// ================= K2: [fused softmax-s +] GEMM2 =================
// grid NB*4 (batch, d-quarter of 192), 512 thr = 8 waves (dw 0..3 x qw 0..1).
// XCD-paired swizzle: all 4 quarters of a batch share an XCD (ws logits L2 hits).
// FUSED: logits from ws + softmax-s in LDS + attn_map write.  else: attn fp32 from Aout.
template<bool FUSED>
__global__ __launch_bounds__(512, 4) void k2_gemm2(
    const float* __restrict__ Cg, const unsigned short* __restrict__ WsLog,
    const float* __restrict__ AttnF, float* __restrict__ Wout, float* __restrict__ AoutF)
{
    extern __shared__ char smem2[];
    unsigned short* sP = (unsigned short*)smem2;      // [96][LDP]
    unsigned* sPd = (unsigned*)smem2;                 // dword view, stride 196
    float* sMax = (float*)(smem2 + NQ * LDP * 2);     // [96]
    float* sInv = sMax + NQ;                          // [96]

    const int x = blockIdx.x;
    const int b = (x & 7) * 32 + (x >> 5);
    const int quarter = (x >> 3) & 3;
    const int tid = threadIdx.x;
    const int wv = tid >> 6;
    const int lane = tid & 63;
    const int ll = lane & 15;
    const int lg = lane >> 4;

    if constexpr (FUSED) {
        // stage raw bf16 logits2 from ws; elems >=361 are garbage (masked below)
        const unsigned* __restrict__ wsd = (const unsigned*)(WsLog + (size_t)b * NQ * WSROW);
        for (int i = tid; i < NQ * 184; i += 512) {
            int r = i / 184, c = i - r * 184;
            sPd[r * 196 + c] = wsd[i];
        }
        for (int i = tid; i < NQ * 12; i += 512) {     // zero pad dwords 184..195
            int r = i / 12, c = i - r * 12;
            sPd[r * 196 + 184 + c] = 0;
        }
        __syncthreads();

        const int l32 = tid & 31;
        const int rbase = tid >> 5;    // 0..15
        // ---- max pass (per q-row over s) ----
#pragma unroll
        for (int pass = 0; pass < 6; ++pass) {
            int row = pass * 16 + rbase;
            float m = -3.0e38f;
#pragma unroll
            for (int j = 0; j < 6; ++j) {
                int dw = l32 + 32 * j;
                if (dw < 184) {
                    unsigned u = sPd[row * 196 + dw];
                    float v0 = bf2f((unsigned short)(u & 0xFFFFu));
                    float v1 = bf2f((unsigned short)(u >> 16));
                    if (2 * dw < NS) m = fmaxf(m, v0);
                    if (2 * dw + 1 < NS) m = fmaxf(m, v1);
                }
            }
#pragma unroll
            for (int o = 1; o < 32; o <<= 1) m = fmaxf(m, __shfl_xor(m, o));
            if (l32 == 0) sMax[row] = m;
        }
        __syncthreads();
        // ---- exp pass: store unnormalized exp as bf16; row sums ----
#pragma unroll
        for (int pass = 0; pass < 6; ++pass) {
            int row = pass * 16 + rbase;
            float m = sMax[row];
            float sum = 0.0f;
#pragma unroll
            for (int j = 0; j < 6; ++j) {
                int dw = l32 + 32 * j;
                if (dw < 184) {
                    unsigned u = sPd[row * 196 + dw];
                    float v0 = bf2f((unsigned short)(u & 0xFFFFu));
                    float v1 = bf2f((unsigned short)(u >> 16));
                    float e0 = (2 * dw < NS) ? __expf(v0 - m) : 0.0f;
                    float e1 = (2 * dw + 1 < NS) ? __expf(v1 - m) : 0.0f;
                    sum += e0 + e1;
                    sPd[row * 196 + dw] = ((unsigned)f2bf(e1) << 16) | (unsigned)f2bf(e0);
                }
            }
#pragma unroll
            for (int o = 1; o < 32; o <<= 1) sum += __shfl_xor(sum, o);
            if (l32 == 0) sInv[row] = sum;
        }
        __syncthreads();
        if (tid < NQ) sInv[tid] = 1.0f / sInv[tid];
        __syncthreads();
        if (quarter == 0) {   // write attn_map once per batch
            float* aout = AoutF + (size_t)b * NQ * NS;
            for (int i = tid; i < NQ * NS; i += 512) {
                int q = i / NS, s = i - q * NS;
                aout[i] = bf2f(sP[q * LDP + s]) * sInv[q];
            }
        }
    } else {
        // stage softmaxed fp32 attn -> bf16
        const float* __restrict__ attn = AttnF + (size_t)b * NQ * NS;
        for (int i = tid; i < NQ * 181; i += 512) {
            int row = i / 181, p = i - row * 181;
            float x0 = attn[row * NS + 2 * p];
            float x1 = (p < 180) ? attn[row * NS + 2 * p + 1] : 0.0f;
            sPd[row * 196 + p] = pack_hi(__float_as_uint(x1), __float_as_uint(x0));
        }
        for (int i = tid; i < NQ * 15; i += 512) {
            int row = i / 15, p = i - row * 15;
            sPd[row * 196 + 181 + p] = 0;
        }
        __syncthreads();
    }

    // ---- GEMM2 main loop: A = ctx rows (fp32 direct + perm), B = sP ----
    f32x4_t acc[3][3];
#pragma unroll
    for (int i = 0; i < 3; ++i)
#pragma unroll
        for (int j = 0; j < 3; ++j) acc[i][j] = (f32x4_t)0.0f;

    const int dw = wv >> 1, qw = wv & 1;
    const float* __restrict__ cq = Cg + (size_t)b * NDF * NS + (size_t)(quarter * 192) * NS;

#pragma unroll
    for (int c = 0; c < 12; ++c) {
        bf16x8_t Bf[3];
#pragma unroll
        for (int nt = 0; nt < 3; ++nt) {
            int row = 16 * (3 * qw + nt) + ll;
            Bf[nt] = *(const bf16x8_t*)&sP[row * LDP + 32 * c + 8 * lg];
        }
#pragma unroll
        for (int i = 0; i < 3; ++i) {
            int d = 16 * (3 * dw + i) + ll;
            const float* ap = cq + (size_t)d * NS + 32 * c + 8 * lg;
            u32x4_t u;
            if (c < 11) {
                f32x4u_t a0 = *(const f32x4u_t*)ap;
                f32x4u_t a1 = *(const f32x4u_t*)(ap + 4);
                u[0] = pack_hi(__float_as_uint(a0[1]), __float_as_uint(a0[0]));
                u[1] = pack_hi(__float_as_uint(a0[3]), __float_as_uint(a0[2]));
                u[2] = pack_hi(__float_as_uint(a1[1]), __float_as_uint(a1[0]));
                u[3] = pack_hi(__float_as_uint(a1[3]), __float_as_uint(a1[2]));
            } else {
                float t[8];
#pragma unroll
                for (int e = 0; e < 8; ++e) {
                    int s = 352 + 8 * lg + e;
                    t[e] = (s < NS) ? ap[e] : 0.0f;
                }
                u[0] = pack_hi(__float_as_uint(t[1]), __float_as_uint(t[0]));
                u[1] = pack_hi(__float_as_uint(t[3]), __float_as_uint(t[2]));
                u[2] = pack_hi(__float_as_uint(t[5]), __float_as_uint(t[4]));
                u[3] = pack_hi(__float_as_uint(t[7]), __float_as_uint(t[6]));
            }
            bf16x8_t Af = __builtin_bit_cast(bf16x8_t, u);
#pragma unroll
            for (int nt = 0; nt < 3; ++nt)
                acc[i][nt] = __builtin_amdgcn_mfma_f32_16x16x32_bf16(Af, Bf[nt], acc[i][nt], 0, 0, 0);
        }
    }

    float* wout = Wout + (size_t)b * NDF * NQ;
    float invq[3];
#pragma unroll
    for (int nt = 0; nt < 3; ++nt) {
        if constexpr (FUSED) invq[nt] = sInv[16 * (3 * qw + nt) + ll];
        else invq[nt] = 1.0f;
    }
#pragma unroll
    for (int i = 0; i < 3; ++i)
#pragma unroll
        for (int nt = 0; nt < 3; ++nt)
#pragma unroll
            for (int r = 0; r < 4; ++r) {
                int d = quarter * 192 + 16 * (3 * dw + i) + 4 * lg + r;
                int q = 16 * (3 * qw + nt) + ll;
                wout[(size_t)d * NQ + q] = acc[i][nt][r] * invq[nt];
            }
}

extern "C" void kernel_launch(void* const* d_in, const int* in_sizes, int n_in,
                              void* d_out, int out_size, void* d_ws, size_t ws_size,
                              hipStream_t stream) {
    const float* Qg = (const float*)d_in[0];
    const float* Cg = (const float*)d_in[1];
    float* Wout = (float*)d_out;
    float* Aout = Wout + (size_t)NB * NDF * NQ;   // outputs: weighted_context, attn_map

    const int smem2 = NQ * LDP * 2 + NQ * 8;      // 76032 B

    if (ws_size >= WS_LOG_BYTES) {
        unsigned short* wsLog = (unsigned short*)d_ws;
        k1_gemm1_softmaxq<1><<<dim3(NB * 2), dim3(384), 0, stream>>>(Qg, Cg, wsLog, nullptr);
        (void)hipFuncSetAttribute((const void*)k2_gemm2<true>,
                                  hipFuncAttributeMaxDynamicSharedMemorySize, smem2);
        k2_gemm2<true><<<dim3(NB * 4), dim3(512), smem2, stream>>>(
            Cg, wsLog, nullptr, Wout, Aout);
    } else {
        k1_gemm1_softmaxq<0><<<dim3(NB * 2), dim3(384), 0, stream>>>(Qg, Cg, nullptr, Aout);
        k15_softmaxs<<<dim3(NB, 24), dim3(256), 0, stream>>>(Aout);
        (void)hipFuncSetAttribute((const void*)k2_gemm2<false>,
                                  hipFuncAttributeMaxDynamicSharedMemorySize, smem2);
        k2_gemm2<false><<<dim3(NB * 4), dim3(512), smem2, stream>>>(
            Cg, nullptr, Aout, Wout, Aout);
    }
}

// Round 12
// 206.964 us; speedup vs baseline: 1.7117x; 1.7117x over previous
//
#include <hip/hip_runtime.h>

// Problem constants
#define NB 256
#define NDF 768
#define NQ 96
#define NS 361
#define LDT 40        // Q staging stride (bf16 elems): 80B rows
#define LDP 392       // K2 attn LDS stride (bf16 elems): 784B rows, 16B-aligned
#define WSROW 368     // ws logits row stride (bf16 elems): 184 dwords, 16B-aligned
#define WS_LOG_BYTES ((size_t)NB * NQ * WSROW * 2)

typedef short bf16x8_t __attribute__((ext_vector_type(8)));
typedef float f32x4_t __attribute__((ext_vector_type(4)));
typedef float f32x4u_t __attribute__((ext_vector_type(4), aligned(4)));
typedef unsigned int u32x4_t __attribute__((ext_vector_type(4)));

__device__ __forceinline__ unsigned pack_hi(unsigned b_, unsigned a_) {
    return __builtin_amdgcn_perm(b_, a_, 0x07060302u);
}
__device__ __forceinline__ unsigned short f2bf(float x) {   // RNE
    unsigned u = __float_as_uint(x);
    u += 0x7FFFu + ((u >> 16) & 1u);
    return (unsigned short)(u >> 16);
}
__device__ __forceinline__ float bf2f(unsigned short h) {
    return __uint_as_float(((unsigned)h) << 16);
}

// split-bf16 convert: 8 fp32 -> hi bf16x8 (trunc) + lo bf16x8 (residual, trunc)
__device__ __forceinline__ void cvt8(const float* x, bf16x8_t& hi, bf16x8_t& lo) {
    unsigned uh[8]; float fl[8];
#pragma unroll
    for (int j = 0; j < 8; ++j) {
        unsigned u = __float_as_uint(x[j]);
        uh[j] = u;
        fl[j] = x[j] - __uint_as_float(u & 0xFFFF0000u);
    }
    u32x4_t h, l;
    h[0] = pack_hi(uh[1], uh[0]); h[1] = pack_hi(uh[3], uh[2]);
    h[2] = pack_hi(uh[5], uh[4]); h[3] = pack_hi(uh[7], uh[6]);
    l[0] = pack_hi(__float_as_uint(fl[1]), __float_as_uint(fl[0]));
    l[1] = pack_hi(__float_as_uint(fl[3]), __float_as_uint(fl[2]));
    l[2] = pack_hi(__float_as_uint(fl[5]), __float_as_uint(fl[4]));
    l[3] = pack_hi(__float_as_uint(fl[7]), __float_as_uint(fl[6]));
    hi = __builtin_bit_cast(bf16x8_t, h);
    lo = __builtin_bit_cast(bf16x8_t, l);
}

// LDS-only barrier: orders LDS ops; does NOT drain vmcnt (asm loads stay in flight).
__device__ __forceinline__ void block_sync_lds() {
    asm volatile("s_waitcnt lgkmcnt(0)" ::: "memory");
    __builtin_amdgcn_s_barrier();
    __builtin_amdgcn_sched_barrier(0);
}

// Raw asm loads: volatile => issue order pinned, outputs cannot be sunk/rematerialized.
#define GLD(D, A)     asm volatile("global_load_dword %0, %1, off" : "=v"(D) : "v"(A))
#define GLDO(D, A, O) asm volatile("global_load_dword %0, %1, off offset:" #O : "=v"(D) : "v"(A))
// Counted wait + scheduling fence (rule #18: consumers must not hoist past the wait).
#define VMWAIT(N) { asm volatile("s_waitcnt vmcnt(" #N ")"); __builtin_amdgcn_sched_barrier(0); }

// ================= K1: GEMM1 (split-bf16) + softmax over q =================
// grid NB*2 (batch, s-half of 192), 384 thr = 6 waves; wave: 2 s-tiles x 6 q-tiles.
// Software pipeline with manual vmcnt FIFO accounting (ONLY asm VMEM in the loop):
//   enter iter c: in-flight = [ctx(c):16]
//   issue Q(c+1):8, ctx(c+1):16      -> [ctx(c)16, Q8, ctx16] = 40
//   vmcnt(24)  => ctx(c) complete    -> MFMA on ctx(c)
//   vmcnt(16)  => Q(c+1) complete    -> stage Q -> lgkm barrier
// Q LDS tile XOR-swizzled (col8 ^= (row>>3)&3): stores & reads both <=2-way banks.
template<int MODE>
__global__ __launch_bounds__(384, 3) void k1_gemm1_softmaxq(
    const float* __restrict__ Qg, const float* __restrict__ Cg,
    unsigned short* __restrict__ WsLog, float* __restrict__ AoutF)
{
    __shared__ __align__(16) unsigned short sQhi[2][NQ * LDT];
    __shared__ __align__(16) unsigned short sQlo[2][NQ * LDT];

    // XCD-pairing swizzle (grid 512 = 8 xcd * 32 batch-groups * 2 halves)
    const int x = blockIdx.x;
    const int b = (x & 7) * 32 + (x >> 4);
    const int h = (x >> 3) & 1;

    const int tid = threadIdx.x;
    const int wv = tid >> 6;
    const int lane = tid & 63;
    const int ll = lane & 15;
    const int lg = lane >> 4;
    const int llh = (ll >> 3) & 1;
    const int s0 = 192 * h;
    const int qq = tid % 96;
    const int koct = tid / 96;         // 0..3
    const int sc0 = min(s0 + 32 * wv + ll, NS - 1);
    const int sc1 = min(s0 + 32 * wv + 16 + ll, NS - 1);
    // swizzled Q-tile store offset (shorts): row=qq, col8 = koct ^ ((qq>>3)&3)
    const int stoff = qq * LDT + 8 * (koct ^ ((qq >> 3) & 3));

    const float* __restrict__ qg = Qg + (size_t)b * NDF * NQ;   // [768][96]
    const float* __restrict__ cg = Cg + (size_t)b * NDF * NS;   // [768][361]

    f32x4_t acc[6][2];
#pragma unroll
    for (int i = 0; i < 6; ++i)
#pragma unroll
        for (int j = 0; j < 2; ++j) acc[i][j] = (f32x4_t)0.0f;

    float qv[8], cA[16], cB[16];

// 8 Q loads: rows K0+8*koct..+7, col qq. Stride NQ*4 = 384 B -> offset immediates.
#define ISSUE_Q(K0) { \
    unsigned long long qa = (unsigned long long)(qg + ((K0) + 8 * koct) * NQ + qq); \
    GLD (qv[0], qa);        GLDO(qv[1], qa, 384); \
    GLDO(qv[2], qa, 768);   GLDO(qv[3], qa, 1152); \
    GLDO(qv[4], qa, 1536);  GLDO(qv[5], qa, 1920); \
    GLDO(qv[6], qa, 2304);  GLDO(qv[7], qa, 2688); }

// 16 ctx loads: rows K0+8*lg..+7, cols sc0 then sc1. Stride NS*4 = 1444 B.
#define ISSUE_CTX(K0, R) { \
    unsigned long long p0 = (unsigned long long)(cg + (size_t)((K0) + 8 * lg) * NS + sc0); \
    unsigned long long p1 = p0 + 3u * NS * 4u; \
    unsigned long long p2 = p0 + 6u * NS * 4u; \
    GLD (R[0], p0); GLDO(R[1], p0, 1444); GLDO(R[2], p0, 2888); \
    GLD (R[3], p1); GLDO(R[4], p1, 1444); GLDO(R[5], p1, 2888); \
    GLD (R[6], p2); GLDO(R[7], p2, 1444); \
    unsigned long long p3 = (unsigned long long)(cg + (size_t)((K0) + 8 * lg) * NS + sc1); \
    unsigned long long p4 = p3 + 3u * NS * 4u; \
    unsigned long long p5 = p3 + 6u * NS * 4u; \
    GLD (R[8],  p3); GLDO(R[9],  p3, 1444); GLDO(R[10], p3, 2888); \
    GLD (R[11], p4); GLDO(R[12], p4, 1444); GLDO(R[13], p4, 2888); \
    GLD (R[14], p5); GLDO(R[15], p5, 1444); }

#define STAGEQ(CUR) { \
    bf16x8_t qh, ql; \
    cvt8(qv, qh, ql); \
    *(bf16x8_t*)&sQhi[CUR][stoff] = qh; \
    *(bf16x8_t*)&sQlo[CUR][stoff] = ql; }

#define MFMAPH(R, CUR) { \
    bf16x8_t B0h, B0l, B1h, B1l; \
    cvt8(R, B0h, B0l); \
    cvt8(R + 8, B1h, B1l); \
    _Pragma("unroll") \
    for (int mt = 0; mt < 6; ++mt) { \
        int ro = (16 * mt + ll) * LDT + 8 * (lg ^ ((2 * mt + llh) & 3)); \
        bf16x8_t Ah = *(const bf16x8_t*)&sQhi[CUR][ro]; \
        bf16x8_t Al = *(const bf16x8_t*)&sQlo[CUR][ro]; \
        acc[mt][0] = __builtin_amdgcn_mfma_f32_16x16x32_bf16(Ah, B0h, acc[mt][0], 0, 0, 0); \
        acc[mt][0] = __builtin_amdgcn_mfma_f32_16x16x32_bf16(Ah, B0l, acc[mt][0], 0, 0, 0); \
        acc[mt][0] = __builtin_amdgcn_mfma_f32_16x16x32_bf16(Al, B0h, acc[mt][0], 0, 0, 0); \
        acc[mt][1] = __builtin_amdgcn_mfma_f32_16x16x32_bf16(Ah, B1h, acc[mt][1], 0, 0, 0); \
        acc[mt][1] = __builtin_amdgcn_mfma_f32_16x16x32_bf16(Ah, B1l, acc[mt][1], 0, 0, 0); \
        acc[mt][1] = __builtin_amdgcn_mfma_f32_16x16x32_bf16(Al, B1h, acc[mt][1], 0, 0, 0); } }

// One pipeline iteration for chunk C (uses USE set, fills FILL set).
#define ITER(C, USE, FILL, CUR, NXT) { \
    ISSUE_Q(((C) + 1) * 32); \
    ISSUE_CTX(((C) + 1) * 32, FILL); \
    VMWAIT(24); \
    MFMAPH(USE, CUR); \
    VMWAIT(16); \
    STAGEQ(NXT); \
    block_sync_lds(); }

    // prologue: in-flight becomes [Q(0):8, ctx(0):16]; vmcnt(16) completes Q(0)
    ISSUE_Q(0);
    ISSUE_CTX(0, cA);
    VMWAIT(16);
    STAGEQ(0);
    block_sync_lds();

    for (int c = 0; c < 22; c += 2) {
        ITER(c,     cA, cB, 0, 1);
        ITER(c + 1, cB, cA, 1, 0);
    }
    ITER(22, cA, cB, 0, 1);   // issues Q(23), ctx(23)->cB; stages Q into buf1
    VMWAIT(0);                // ctx(23) complete
    MFMAPH(cB, 1);

#undef ISSUE_Q
#undef ISSUE_CTX
#undef STAGEQ
#undef MFMAPH
#undef ITER

    // softmax over q (per s-col), fold *4; D layout: col(s)=ll, row(q)=16mt+4lg+r
#pragma unroll
    for (int nt = 0; nt < 2; ++nt) {
        float m = -3.0e38f;
#pragma unroll
        for (int mt = 0; mt < 6; ++mt)
#pragma unroll
            for (int r = 0; r < 4; ++r) m = fmaxf(m, acc[mt][nt][r]);
        m = fmaxf(m, __shfl_xor(m, 16));
        m = fmaxf(m, __shfl_xor(m, 32));
        float sum = 0.0f;
#pragma unroll
        for (int mt = 0; mt < 6; ++mt)
#pragma unroll
            for (int r = 0; r < 4; ++r) {
                float e = __expf(acc[mt][nt][r] - m);
                acc[mt][nt][r] = e;
                sum += e;
            }
        sum += __shfl_xor(sum, 16);
        sum += __shfl_xor(sum, 32);
        float inv = 4.0f / sum;     // fold TEMP1
#pragma unroll
        for (int mt = 0; mt < 6; ++mt)
#pragma unroll
            for (int r = 0; r < 4; ++r) acc[mt][nt][r] *= inv;
    }

    if constexpr (MODE >= 1) {
        unsigned short* wr = WsLog + (size_t)b * NQ * WSROW;
#pragma unroll
        for (int mt = 0; mt < 6; ++mt)
#pragma unroll
            for (int nt = 0; nt < 2; ++nt)
#pragma unroll
                for (int r = 0; r < 4; ++r) {
                    int q = 16 * mt + 4 * lg + r;
                    int s = s0 + 32 * wv + 16 * nt + ll;
                    if (s < NS) wr[q * WSROW + s] = f2bf(acc[mt][nt][r]);
                }
    } else {
        float* aout = AoutF + (size_t)b * NQ * NS;
#pragma unroll
        for (int mt = 0; mt < 6; ++mt)
#pragma unroll
            for (int nt = 0; nt < 2; ++nt)
#pragma unroll
                for (int r = 0; r < 4; ++r) {
                    int q = 16 * mt + 4 * lg + r;
                    int s = s0 + 32 * wv + 16 * nt + ll;
                    if (s < NS) aout[(size_t)q * NS + s] = acc[mt][nt][r];
                }
    }
}

// ================= K15 (fallback only): in-place softmax over s =================
__global__ __launch_bounds__(256) void k15_softmaxs(float* __restrict__ Aout)
{
    const int b = blockIdx.x;
    const int q = blockIdx.y * 4 + (threadIdx.x >> 6);
    const int lane = threadIdx.x & 63;
    float* __restrict__ row = Aout + ((size_t)b * NQ + q) * NS;
    const int c0 = 6 * lane;

    float v[6];
#pragma unroll
    for (int i = 0; i < 6; ++i) v[i] = (c0 + i < NS) ? row[c0 + i] : -INFINITY;
    float m = v[0];
#pragma unroll
    for (int i = 1; i < 6; ++i) m = fmaxf(m, v[i]);
#pragma unroll
    for (int o = 1; o < 64; o <<= 1) m = fmaxf(m, __shfl_xor(m, o));
    float e[6], sum = 0.0f;
#pragma unroll
    for (int i = 0; i < 6; ++i) { e[i] = __expf(v[i] - m); sum += e[i]; }
#pragma unroll
    for (int o = 1; o < 64; o <<= 1) sum += __shfl_xor(sum, o);
    float inv = 1.0f / sum;
#pragma unroll
    for (int i = 0; i < 6; ++i) if (c0 + i < NS) row[c0 + i] = e[i] * inv;
}

// ================= K2: [fused softmax-s +] GEMM2 (unchanged from r10) =================
template<bool FUSED>
__global__ __launch_bounds__(512, 4) void k2_gemm2(
    const float* __restrict__ Cg, const unsigned short* __restrict__ WsLog,
    const float* __restrict__ AttnF, float* __restrict__ Wout, float* __restrict__ AoutF)
{
    extern __shared__ char smem2[];
    unsigned short* sP = (unsigned short*)smem2;      // [96][LDP]
    unsigned* sPd = (unsigned*)smem2;                 // dword view, stride 196
    float* sMax = (float*)(smem2 + NQ * LDP * 2);     // [96]
    float* sInv = sMax + NQ;                          // [96]

    const int x = blockIdx.x;
    const int b = (x & 7) * 32 + (x >> 5);
    const int quarter = (x >> 3) & 3;
    const int tid = threadIdx.x;
    const int wv = tid >> 6;
    const int lane = tid & 63;
    const int ll = lane & 15;
    const int lg = lane >> 4;

    if constexpr (FUSED) {
        const unsigned* __restrict__ wsd = (const unsigned*)(WsLog + (size_t)b * NQ * WSROW);
        for (int i = tid; i < NQ * 184; i += 512) {
            int r = i / 184, c = i - r * 184;
            sPd[r * 196 + c] = wsd[i];
        }
        for (int i = tid; i < NQ * 12; i += 512) {
            int r = i / 12, c = i - r * 12;
            sPd[r * 196 + 184 + c] = 0;
        }
        __syncthreads();

        const int l32 = tid & 31;
        const int rbase = tid >> 5;
#pragma unroll
        for (int pass = 0; pass < 6; ++pass) {
            int row = pass * 16 + rbase;
            float m = -3.0e38f;
#pragma unroll
            for (int j = 0; j < 6; ++j) {
                int dw = l32 + 32 * j;
                if (dw < 184) {
                    unsigned u = sPd[row * 196 + dw];
                    float v0 = bf2f((unsigned short)(u & 0xFFFFu));
                    float v1 = bf2f((unsigned short)(u >> 16));
                    if (2 * dw < NS) m = fmaxf(m, v0);
                    if (2 * dw + 1 < NS) m = fmaxf(m, v1);
                }
            }
#pragma unroll
            for (int o = 1; o < 32; o <<= 1) m = fmaxf(m, __shfl_xor(m, o));
            if (l32 == 0) sMax[row] = m;
        }
        __syncthreads();
#pragma unroll
        for (int pass = 0; pass < 6; ++pass) {
            int row = pass * 16 + rbase;
            float m = sMax[row];
            float sum = 0.0f;
#pragma unroll
            for (int j = 0; j < 6; ++j) {
                int dw = l32 + 32 * j;
                if (dw < 184) {
                    unsigned u = sPd[row * 196 + dw];
                    float v0 = bf2f((unsigned short)(u & 0xFFFFu));
                    float v1 = bf2f((unsigned short)(u >> 16));
                    float e0 = (2 * dw < NS) ? __expf(v0 - m) : 0.0f;
                    float e1 = (2 * dw + 1 < NS) ? __expf(v1 - m) : 0.0f;
                    sum += e0 + e1;
                    sPd[row * 196 + dw] = ((unsigned)f2bf(e1) << 16) | (unsigned)f2bf(e0);
                }
            }
#pragma unroll
            for (int o = 1; o < 32; o <<= 1) sum += __shfl_xor(sum, o);
            if (l32 == 0) sInv[row] = sum;
        }
        __syncthreads();
        if (tid < NQ) sInv[tid] = 1.0f / sInv[tid];
        __syncthreads();
        if (quarter == 0) {
            float* aout = AoutF + (size_t)b * NQ * NS;
            for (int i = tid; i < NQ * NS; i += 512) {
                int q = i / NS, s = i - q * NS;
                aout[i] = bf2f(sP[q * LDP + s]) * sInv[q];
            }
        }
    } else {
        const float* __restrict__ attn = AttnF + (size_t)b * NQ * NS;
        for (int i = tid; i < NQ * 181; i += 512) {
            int row = i / 181, p = i - row * 181;
            float x0 = attn[row * NS + 2 * p];
            float x1 = (p < 180) ? attn[row * NS + 2 * p + 1] : 0.0f;
            sPd[row * 196 + p] = pack_hi(__float_as_uint(x1), __float_as_uint(x0));
        }
        for (int i = tid; i < NQ * 15; i += 512) {
            int row = i / 15, p = i - row * 15;
            sPd[row * 196 + 181 + p] = 0;
        }
        __syncthreads();
    }

    f32x4_t acc[3][3];
#pragma unroll
    for (int i = 0; i < 3; ++i)
#pragma unroll
        for (int j = 0; j < 3; ++j) acc[i][j] = (f32x4_t)0.0f;

    const int dw = wv >> 1, qw = wv & 1;
    const float* __restrict__ cq = Cg + (size_t)b * NDF * NS + (size_t)(quarter * 192) * NS;

#pragma unroll
    for (int c = 0; c < 12; ++c) {
        bf16x8_t Bf[3];
#pragma unroll
        for (int nt = 0; nt < 3; ++nt) {
            int row = 16 * (3 * qw + nt) + ll;
            Bf[nt] = *(const bf16x8_t*)&sP[row * LDP + 32 * c + 8 * lg];
        }
#pragma unroll
        for (int i = 0; i < 3; ++i) {
            int d = 16 * (3 * dw + i) + ll;
            const float* ap = cq + (size_t)d * NS + 32 * c + 8 * lg;
            u32x4_t u;
            if (c < 11) {
                f32x4u_t a0 = *(const f32x4u_t*)ap;
                f32x4u_t a1 = *(const f32x4u_t*)(ap + 4);
                u[0] = pack_hi(__float_as_uint(a0[1]), __float_as_uint(a0[0]));
                u[1] = pack_hi(__float_as_uint(a0[3]), __float_as_uint(a0[2]));
                u[2] = pack_hi(__float_as_uint(a1[1]), __float_as_uint(a1[0]));
                u[3] = pack_hi(__float_as_uint(a1[3]), __float_as_uint(a1[2]));
            } else {
                float t[8];
#pragma unroll
                for (int e = 0; e < 8; ++e) {
                    int s = 352 + 8 * lg + e;
                    t[e] = (s < NS) ? ap[e] : 0.0f;
                }
                u[0] = pack_hi(__float_as_uint(t[1]), __float_as_uint(t[0]));
                u[1] = pack_hi(__float_as_uint(t[3]), __float_as_uint(t[2]));
                u[2] = pack_hi(__float_as_uint(t[5]), __float_as_uint(t[4]));
                u[3] = pack_hi(__float_as_uint(t[7]), __float_as_uint(t[6]));
            }
            bf16x8_t Af = __builtin_bit_cast(bf16x8_t, u);
#pragma unroll
            for (int nt = 0; nt < 3; ++nt)
                acc[i][nt] = __builtin_amdgcn_mfma_f32_16x16x32_bf16(Af, Bf[nt], acc[i][nt], 0, 0, 0);
        }
    }

    float* wout = Wout + (size_t)b * NDF * NQ;
    float invq[3];
#pragma unroll
    for (int nt = 0; nt < 3; ++nt) {
        if constexpr (FUSED) invq[nt] = sInv[16 * (3 * qw + nt) + ll];
        else invq[nt] = 1.0f;
    }
#pragma unroll
    for (int i = 0; i < 3; ++i)
#pragma unroll
        for (int nt = 0; nt < 3; ++nt)
#pragma unroll
            for (int r = 0; r < 4; ++r) {
                int d = quarter * 192 + 16 * (3 * dw + i) + 4 * lg + r;
                int q = 16 * (3 * qw + nt) + ll;
                wout[(size_t)d * NQ + q] = acc[i][nt][r] * invq[nt];
            }
}

extern "C" void kernel_launch(void* const* d_in, const int* in_sizes, int n_in,
                              void* d_out, int out_size, void* d_ws, size_t ws_size,
                              hipStream_t stream) {
    const float* Qg = (const float*)d_in[0];
    const float* Cg = (const float*)d_in[1];
    float* Wout = (float*)d_out;
    float* Aout = Wout + (size_t)NB * NDF * NQ;   // outputs: weighted_context, attn_map

    const int smem2 = NQ * LDP * 2 + NQ * 8;      // 76032 B

    if (ws_size >= WS_LOG_BYTES) {
        unsigned short* wsLog = (unsigned short*)d_ws;
        k1_gemm1_softmaxq<1><<<dim3(NB * 2), dim3(384), 0, stream>>>(Qg, Cg, wsLog, nullptr);
        (void)hipFuncSetAttribute((const void*)k2_gemm2<true>,
                                  hipFuncAttributeMaxDynamicSharedMemorySize, smem2);
        k2_gemm2<true><<<dim3(NB * 4), dim3(512), smem2, stream>>>(
            Cg, wsLog, nullptr, Wout, Aout);
    } else {
        k1_gemm1_softmaxq<0><<<dim3(NB * 2), dim3(384), 0, stream>>>(Qg, Cg, nullptr, Aout);
        k15_softmaxs<<<dim3(NB, 24), dim3(256), 0, stream>>>(Aout);
        (void)hipFuncSetAttribute((const void*)k2_gemm2<false>,
                                  hipFuncAttributeMaxDynamicSharedMemorySize, smem2);
        k2_gemm2<false><<<dim3(NB * 4), dim3(512), smem2, stream>>>(
            Cg, nullptr, Aout, Wout, Aout);
    }
}